// Round 1
// baseline (755.564 us; speedup 1.0000x reference)
//
#include <hip/hip_runtime.h>
#include <stdint.h>

typedef unsigned short u16;
typedef float f32x4 __attribute__((ext_vector_type(4)));
typedef __bf16 bf16x8 __attribute__((ext_vector_type(8)));
typedef unsigned short u16x4 __attribute__((ext_vector_type(4)));
typedef unsigned short u16x8 __attribute__((ext_vector_type(8)));

__device__ __forceinline__ u16 f2bf(float f) {
    union { float f; uint32_t u; } v; v.f = f;
    return (u16)((v.u + 0x7FFFu + ((v.u >> 16) & 1u)) >> 16);
}

// ---------------- weight conversion: f32 -> bf16, same layout ----------------
__global__ __launch_bounds__(256) void k_cvt_w(const float* __restrict__ s, u16* __restrict__ d)
{
    int i = blockIdx.x * 256 + threadIdx.x;   // 1024 blocks * 256 = 262144 = 1M/4
    f32x4 v = *(const f32x4*)(s + (size_t)i * 4);
    u16x4 o; o[0] = f2bf(v[0]); o[1] = f2bf(v[1]); o[2] = f2bf(v[2]); o[3] = f2bf(v[3]);
    *(u16x4*)(d + (size_t)i * 4) = o;
}

// ------------- w_out transpose: [hd=1024][e=1024] f32 -> [e][hd] bf16 -------------
__global__ __launch_bounds__(256) void k_transpose_w(const float* __restrict__ s, u16* __restrict__ d)
{
    __shared__ float t[64][65];
    const int tx = threadIdx.x;
    const int r0 = blockIdx.y << 6;  // hd base
    const int c0 = blockIdx.x << 6;  // e base
#pragma unroll
    for (int it = 0; it < 4; ++it) {
        int g = tx + (it << 8);
        int r = g >> 4, c = (g & 15) << 2;
        f32x4 v = *(const f32x4*)(s + (size_t)(r0 + r) * 1024 + c0 + c);
        t[r][c] = v[0]; t[r][c + 1] = v[1]; t[r][c + 2] = v[2]; t[r][c + 3] = v[3];
    }
    __syncthreads();
#pragma unroll
    for (int it = 0; it < 4; ++it) {
        int g = tx + (it << 8);
        int e = g >> 4, hd = (g & 15) << 2;
        u16x4 o;
        o[0] = f2bf(t[hd][e]); o[1] = f2bf(t[hd + 1][e]);
        o[2] = f2bf(t[hd + 2][e]); o[3] = f2bf(t[hd + 3][e]);
        *(u16x4*)(d + (size_t)(c0 + e) * 1024 + r0 + hd) = o;
    }
}

// ---------------- generic 128x128x64-tile bf16 MFMA GEMM ----------------
// C[M,N] = A[M,1024] * B[N,1024]^T   (both operands [outer][k], k contiguous, K=1024)
// A_F32: A is f32 (converted during staging) else bf16.
// OUT_MODE 0: bf16 store to seq-last layout Xt[h][b][d][m]  (i=(b,m), j=(h,d))
// OUT_MODE 1: f32 store to Out[col*1024 + row]  (row=e dim, col=i dim; 16B stores)
template<int A_F32, int OUT_MODE>
__global__ __launch_bounds__(256)
void gemm_k(const void* __restrict__ Ap, const u16* __restrict__ Bp, void* __restrict__ Op)
{
    __shared__ u16 As[128 * 72];
    __shared__ u16 Bs[128 * 72];

    const int tid = threadIdx.x;
    const int lane = tid & 63;
    const int wid = tid >> 6;
    const int wm = wid >> 1, wn = wid & 1;      // 2x2 wave grid, each 64x64
    const int fr = lane & 15, kb = lane >> 4;

    const int ar0 = blockIdx.y * 128;
    const int br0 = blockIdx.x * 128;

    f32x4 acc[4][4] = {};

    for (int k0 = 0; k0 < 1024; k0 += 64) {
        __syncthreads();
        if (A_F32) {
            const float* A = (const float*)Ap;
#pragma unroll
            for (int it = 0; it < 8; ++it) {
                int g = tid + 256 * it;
                int r = g >> 4, c = (g & 15) << 2;
                f32x4 v = *(const f32x4*)(A + (size_t)(ar0 + r) * 1024 + k0 + c);
                u16x4 o; o[0] = f2bf(v[0]); o[1] = f2bf(v[1]); o[2] = f2bf(v[2]); o[3] = f2bf(v[3]);
                *(u16x4*)(As + r * 72 + c) = o;
            }
        } else {
            const u16* A = (const u16*)Ap;
#pragma unroll
            for (int it = 0; it < 4; ++it) {
                int g = tid + 256 * it;
                int r = g >> 3, c = (g & 7) << 3;
                u16x8 v = *(const u16x8*)(A + (size_t)(ar0 + r) * 1024 + k0 + c);
                *(u16x8*)(As + r * 72 + c) = v;
            }
        }
#pragma unroll
        for (int it = 0; it < 4; ++it) {
            int g = tid + 256 * it;
            int r = g >> 3, c = (g & 7) << 3;
            u16x8 v = *(const u16x8*)(Bp + (size_t)(br0 + r) * 1024 + k0 + c);
            *(u16x8*)(Bs + r * 72 + c) = v;
        }
        __syncthreads();

        bf16x8 af[4][2], bfv[4][2];
#pragma unroll
        for (int mi = 0; mi < 4; ++mi)
#pragma unroll
            for (int ks = 0; ks < 2; ++ks)
                af[mi][ks] = *(const bf16x8*)(As + (wm * 64 + mi * 16 + fr) * 72 + ks * 32 + kb * 8);
#pragma unroll
        for (int ni = 0; ni < 4; ++ni)
#pragma unroll
            for (int ks = 0; ks < 2; ++ks)
                bfv[ni][ks] = *(const bf16x8*)(Bs + (wn * 64 + ni * 16 + fr) * 72 + ks * 32 + kb * 8);

#pragma unroll
        for (int ks = 0; ks < 2; ++ks)
#pragma unroll
            for (int mi = 0; mi < 4; ++mi)
#pragma unroll
                for (int ni = 0; ni < 4; ++ni)
                    acc[mi][ni] = __builtin_amdgcn_mfma_f32_16x16x32_bf16(
                        af[mi][ks], bfv[ni][ks], acc[mi][ni], 0, 0, 0);
    }

    if (OUT_MODE == 0) {
        u16* Out = (u16*)Op;
#pragma unroll
        for (int mi = 0; mi < 4; ++mi) {
#pragma unroll
            for (int ni = 0; ni < 4; ++ni) {
                int i = ar0 + wm * 64 + mi * 16 + ((lane >> 4) << 2);   // 4 consecutive i (=m)
                int j = br0 + wn * 64 + ni * 16 + (lane & 15);
                int b = i >> 11, m = i & 2047;
                int h = j >> 6, d = j & 63;
                u16x4 o;
                o[0] = f2bf(acc[mi][ni][0]); o[1] = f2bf(acc[mi][ni][1]);
                o[2] = f2bf(acc[mi][ni][2]); o[3] = f2bf(acc[mi][ni][3]);
                *(u16x4*)(Out + ((size_t)((h * 4 + b) * 64 + d) << 11) + m) = o;
            }
        }
    } else {
        float* Out = (float*)Op;
#pragma unroll
        for (int mi = 0; mi < 4; ++mi) {
#pragma unroll
            for (int ni = 0; ni < 4; ++ni) {
                int e = ar0 + wm * 64 + mi * 16 + ((lane >> 4) << 2);   // 4 consecutive e
                int i = br0 + wn * 64 + ni * 16 + (lane & 15);
                *(f32x4*)(Out + (size_t)i * 1024 + e) = acc[mi][ni];
            }
        }
    }
}

// ---------------- causal per-head block matmul ----------------
// Yt[n=(b,d)][l] = sum_{m<=l} Xt[h][n][m] * mat2[h][l][m];  write Ynat[b][l][h*64+d] (opt. ReLU)
// block: all 256 n-rows x 64 l-cols; K-loop over m, tril-masked during staging.
template<int RELU>
__global__ __launch_bounds__(256)
void causal_k(const u16* __restrict__ Xt, const float* __restrict__ Amat, u16* __restrict__ Ynat)
{
    __shared__ u16 Xs[256 * 72];
    __shared__ u16 Ms[64 * 72];

    const int bid = blockIdx.x;                       // 512 blocks
    // heavy l-tiles dispatched first; second half pairs light with heavy
    const int lb = (bid < 256) ? (31 - (bid >> 4)) : ((bid - 256) >> 4);
    const int h = bid & 15;
    const int l0 = lb << 6;

    const int tid = threadIdx.x;
    const int lane = tid & 63;
    const int w = tid >> 6;                            // wave: n-range w*64
    const int fr = lane & 15, kb = lane >> 4;

    const u16* X = Xt + (size_t)h * 256 * 2048;
    const float* A = Amat + (size_t)h * 2048 * 2048;

    f32x4 acc[4][4] = {};
    const int nk = lb + 1;

    for (int kt = 0; kt < nk; ++kt) {
        const int k0 = kt << 6;
        __syncthreads();
#pragma unroll
        for (int it = 0; it < 8; ++it) {              // Xs: 256 x 64 bf16
            int g = tid + 256 * it;
            int r = g >> 3, c = (g & 7) << 3;
            u16x8 v = *(const u16x8*)(X + (size_t)r * 2048 + k0 + c);
            *(u16x8*)(Xs + r * 72 + c) = v;
        }
#pragma unroll
        for (int it = 0; it < 4; ++it) {              // Ms: 64 x 64 f32 -> bf16, tril mask
            int g = tid + 256 * it;
            int r = g >> 4, c = (g & 15) << 2;
            f32x4 v = *(const f32x4*)(A + (size_t)(l0 + r) * 2048 + k0 + c);
            u16x4 o;
#pragma unroll
            for (int q = 0; q < 4; ++q)
                o[q] = (k0 + c + q <= l0 + r) ? f2bf(v[q]) : (u16)0;
            *(u16x4*)(Ms + r * 72 + c) = o;
        }
        __syncthreads();

        bf16x8 af[4][2], bfv[4][2];
#pragma unroll
        for (int mi = 0; mi < 4; ++mi)
#pragma unroll
            for (int ks = 0; ks < 2; ++ks)
                af[mi][ks] = *(const bf16x8*)(Xs + (w * 64 + mi * 16 + fr) * 72 + ks * 32 + kb * 8);
#pragma unroll
        for (int ni = 0; ni < 4; ++ni)
#pragma unroll
            for (int ks = 0; ks < 2; ++ks)
                bfv[ni][ks] = *(const bf16x8*)(Ms + (ni * 16 + fr) * 72 + ks * 32 + kb * 8);

#pragma unroll
        for (int ks = 0; ks < 2; ++ks)
#pragma unroll
            for (int mi = 0; mi < 4; ++mi)
#pragma unroll
                for (int ni = 0; ni < 4; ++ni)
                    acc[mi][ni] = __builtin_amdgcn_mfma_f32_16x16x32_bf16(
                        af[mi][ks], bfv[ni][ks], acc[mi][ni], 0, 0, 0);
    }

#pragma unroll
    for (int mi = 0; mi < 4; ++mi) {
#pragma unroll
        for (int ni = 0; ni < 4; ++ni) {
            int n = w * 64 + mi * 16 + ((lane >> 4) << 2);   // 4 consecutive n (=d)
            int l = l0 + ni * 16 + (lane & 15);
            int b = n >> 6, d = n & 63;
            u16x4 o;
#pragma unroll
            for (int q = 0; q < 4; ++q) {
                float f = acc[mi][ni][q];
                if (RELU) f = fmaxf(f, 0.0f);
                o[q] = f2bf(f);
            }
            *(u16x4*)(Ynat + ((size_t)((b << 11) + l) << 10) + (h << 6) + d) = o;
        }
    }
}

extern "C" void kernel_launch(void* const* d_in, const int* in_sizes, int n_in,
                              void* d_out, int out_size, void* d_ws, size_t ws_size,
                              hipStream_t stream)
{
    const float* x     = (const float*)d_in[0];
    const float* W1a   = (const float*)d_in[1];
    const float* W1b   = (const float*)d_in[2];
    const float* mat2a = (const float*)d_in[3];
    const float* mat2b = (const float*)d_in[4];
    const float* wout  = (const float*)d_in[5];

    char* p = (char*)d_ws;
    u16* W1a_bf = (u16*)p; p += (size_t)1024 * 1024 * 2;
    u16* W1b_bf = (u16*)p; p += (size_t)1024 * 1024 * 2;
    u16* Wt_bf  = (u16*)p; p += (size_t)1024 * 1024 * 2;
    u16* Xt     = (u16*)p; p += (size_t)8192 * 1024 * 2;   // seq-last intermediate
    u16* Ynat   = (u16*)p; p += (size_t)8192 * 1024 * 2;   // natural-layout intermediate

    k_cvt_w<<<1024, 256, 0, stream>>>(W1a, W1a_bf);
    k_cvt_w<<<1024, 256, 0, stream>>>(W1b, W1b_bf);
    k_transpose_w<<<dim3(16, 16), 256, 0, stream>>>(wout, Wt_bf);

    // stage 1: x @ W1a^T  -> Xt (seq-last bf16)
    gemm_k<1, 0><<<dim3(8, 64), 256, 0, stream>>>(x, W1a_bf, Xt);
    // stage 2: tril(mat2a) causal matmul + ReLU -> Ynat
    causal_k<1><<<512, 256, 0, stream>>>(Xt, mat2a, Ynat);
    // stage 3: y @ W1b^T -> Xt (reuse)
    gemm_k<0, 0><<<dim3(8, 64), 256, 0, stream>>>(Ynat, W1b_bf, Xt);
    // stage 4: tril(mat2b) causal matmul -> Ynat (reuse)
    causal_k<0><<<512, 256, 0, stream>>>(Xt, mat2b, Ynat);
    // stage 5: out[i][e] = sum_k z[i][k] * w_out[k][e]; swapped operands (A=Wt) for 16B stores
    gemm_k<0, 1><<<dim3(64, 8), 256, 0, stream>>>(Wt_bf, Ynat, d_out);
}